// Round 6
// baseline (232.772 us; speedup 1.0000x reference)
//
#include <hip/hip_runtime.h>
#include <hip/hip_bf16.h>
#include <hip/hip_fp8.h>
#include <math.h>

#define N 8192
#define D 512
#define BM 128
#define BK 128                          // staging super-chunk (2 MFMA k-steps)
#define NSTRIP 64                       // N / BM
#define S_BLOCKS (NSTRIP * NSTRIP)      // 4096 S tiles
#define TRI (NSTRIP * (NSTRIP + 1) / 2) // 2080
#define G_BLOCKS (2 * TRI)              // 4160 Gram tiles
#define SG_BLOCKS (S_BLOCKS + G_BLOCKS) // 8256

typedef float f32x16 __attribute__((ext_vector_type(16)));
typedef int i32x4 __attribute__((ext_vector_type(4)));
typedef int i32x8 __attribute__((ext_vector_type(8)));

__device__ inline void gload_lds16(const void* g, void* l) {
  __builtin_amdgcn_global_load_lds(
      (const __attribute__((address_space(1))) void*)g,
      (__attribute__((address_space(3))) void*)l, 16, 0, 0);
}

// ---------------- normalize to fp8 e4m3 + exact fp32 diagonal + zero out ----------------
// wave-per-row: 64 lanes x 8 floats = 512 = D; shuffle-only reduction, no barriers.
__global__ __launch_bounds__(256) void norm_kernel(
    const float* __restrict__ z1, const float* __restrict__ z2,
    unsigned char* __restrict__ q1, unsigned char* __restrict__ q2,
    float* __restrict__ diag, float* __restrict__ out) {
  int t = threadIdx.x;
  int lane = t & 63;
  int w = t >> 6;
  int row = blockIdx.x * 4 + w;
  if (blockIdx.x == 0 && t == 0) out[0] = 0.0f; // atomic target (stream-ordered)
  const float4* a = (const float4*)(z1 + (size_t)row * D);
  const float4* b = (const float4*)(z2 + (size_t)row * D);
  float4 xa0 = a[lane], xa1 = a[lane + 64];
  float4 xb0 = b[lane], xb1 = b[lane + 64];
  float ss1 = xa0.x * xa0.x + xa0.y * xa0.y + xa0.z * xa0.z + xa0.w * xa0.w +
              xa1.x * xa1.x + xa1.y * xa1.y + xa1.z * xa1.z + xa1.w * xa1.w;
  float ss2 = xb0.x * xb0.x + xb0.y * xb0.y + xb0.z * xb0.z + xb0.w * xb0.w +
              xb1.x * xb1.x + xb1.y * xb1.y + xb1.z * xb1.z + xb1.w * xb1.w;
  float dd = xa0.x * xb0.x + xa0.y * xb0.y + xa0.z * xb0.z + xa0.w * xb0.w +
             xa1.x * xb1.x + xa1.y * xb1.y + xa1.z * xb1.z + xa1.w * xb1.w;
#pragma unroll
  for (int off = 1; off < 64; off <<= 1) {
    ss1 += __shfl_xor(ss1, off);
    ss2 += __shfl_xor(ss2, off);
    dd  += __shfl_xor(dd,  off);
  }
  float i1 = 1.0f / fmaxf(sqrtf(ss1), 1e-12f);
  float i2 = 1.0f / fmaxf(sqrtf(ss2), 1e-12f);
  float fa[8] = {xa0.x, xa0.y, xa0.z, xa0.w, xa1.x, xa1.y, xa1.z, xa1.w};
  float fb[8] = {xb0.x, xb0.y, xb0.z, xb0.w, xb1.x, xb1.y, xb1.z, xb1.w};
  unsigned int u1[2], u2[2];
#pragma unroll
  for (int g = 0; g < 2; g++) {
    unsigned int v1 = 0, v2 = 0;
#pragma unroll
    for (int e = 0; e < 4; e++) {
      __hip_fp8_e4m3 c1(fa[g * 4 + e] * i1); // OCP e4m3fn
      __hip_fp8_e4m3 c2(fb[g * 4 + e] * i2);
      v1 |= ((unsigned int)c1.__x) << (8 * e);
      v2 |= ((unsigned int)c2.__x) << (8 * e);
    }
    u1[g] = v1; u2[g] = v2;
  }
  ((unsigned int*)q1)[(size_t)row * 128 + lane] = u1[0];
  ((unsigned int*)q1)[(size_t)row * 128 + 64 + lane] = u1[1];
  ((unsigned int*)q2)[(size_t)row * 128 + lane] = u2[0];
  ((unsigned int*)q2)[(size_t)row * 128 + 64 + lane] = u2[1];
  if (lane == 0) diag[row] = dd * i1 * i2;
}

// ---------------- stage one BK=128 super-chunk: [128 rows][128 B] per matrix ----------
// 8 lanes per row read the row's FULL 128 B line (16 B pieces permuted by the mod-8
// swizzle, folded into the per-thread global base) -> full-cache-line transactions,
// the m97-shape that sustains ~18 B/cy/block (vs 5 B/cy with 64 B half-line reads).
// LDS piece p of row holds global piece p ^ (row&7).
__device__ __forceinline__ void stage_super(
    const unsigned char* pA, const unsigned char* pB,
    unsigned char* buf, int t, int sc) {
  int k0 = sc * BK;
#pragma unroll
  for (int it = 0; it < 4; it++) {
    gload_lds16(pA + (size_t)(it * 32) * D + k0, buf + it * 4096 + t * 16);
    gload_lds16(pB + (size_t)(it * 32) * D + k0, buf + 16384 + it * 4096 + t * 16);
  }
}

// ---------------- one super-round: drain own stage, barrier, stage next, 8 MFMA -------
// m97-proven drain schedule; the stage drained at round p was issued one full round
// (~550 cy MFMA + reads) earlier. Ring-2 reuse safety: stage(p+1) overwrites the buf
// whose ds_reads were lgkm-drained before round p-1's MFMAs, hence before barrier p.
#define SG_ROUND(p)                                                            \
  {                                                                            \
    asm volatile("s_waitcnt vmcnt(0)" ::: "memory");                           \
    __builtin_amdgcn_s_barrier();                                              \
    __builtin_amdgcn_sched_barrier(0);                                         \
    if ((p) < 3) stage_super(pA, pB, lds[((p) + 1) & 1], t, (p) + 1);          \
    const unsigned char* buf = lds[(p) & 1];                                   \
    i32x8 af[2][2], bf[2][2];                                                  \
    _Pragma("unroll")                                                          \
    for (int ks = 0; ks < 2; ks++)                                             \
      _Pragma("unroll")                                                        \
      for (int i = 0; i < 2; i++) {                                            \
        i32x4 lo = *(const i32x4*)(buf + offA[ks][i]);                         \
        i32x4 hi = *(const i32x4*)(buf + (offA[ks][i] ^ 16));                  \
        af[ks][i] = __builtin_shufflevector(lo, hi, 0, 1, 2, 3, 4, 5, 6, 7);   \
        lo = *(const i32x4*)(buf + offB[ks][i]);                               \
        hi = *(const i32x4*)(buf + (offB[ks][i] ^ 16));                        \
        bf[ks][i] = __builtin_shufflevector(lo, hi, 0, 1, 2, 3, 4, 5, 6, 7);   \
      }                                                                        \
    asm volatile("s_waitcnt lgkmcnt(0)" ::: "memory");                         \
    __builtin_amdgcn_sched_barrier(0);                                         \
    __builtin_amdgcn_s_setprio(1);                                             \
    _Pragma("unroll")                                                          \
    for (int ks = 0; ks < 2; ks++)                                             \
      _Pragma("unroll")                                                        \
      for (int i = 0; i < 2; i++)                                              \
        _Pragma("unroll")                                                      \
        for (int j = 0; j < 2; j++)                                            \
          acc[i][j] = __builtin_amdgcn_mfma_scale_f32_32x32x64_f8f6f4(         \
              af[ks][i], bf[ks][j], acc[i][j], 0, 0, 0, 0x7F7F7F7F, 0,         \
              0x7F7F7F7F);                                                     \
    __builtin_amdgcn_s_setprio(0);                                             \
    __builtin_amdgcn_sched_barrier(0);                                         \
  }

// ---------------- fused S + G pass: one 128x128 tile per block, 4 waves ----------------
// 32x32 C/D layout: col = lane&31, row = (reg&3) + 8*(reg>>2) + 4*(lane>>5).
// Fragment reads: piece = (4ks+2h) ^ (row&7); over 32 consecutive rows this covers
// all 32 banks uniformly (4 lanes/bank = ds_read_b128 minimum -> conflict-free).
__global__ __launch_bounds__(256, 2) void sg_kernel(
    const unsigned char* __restrict__ q1, const unsigned char* __restrict__ q2,
    float* __restrict__ rowS, float* __restrict__ colS,
    float* __restrict__ partG) {
  __shared__ unsigned char lds[2][32768]; // ring-2 x [A 16KB | B 16KB]
  // reductions alias slot 0 (dead after k-loop; guarded by barrier)
  float (*redA)[BM] = reinterpret_cast<float (*)[BM]>(&lds[0][0]);
  float (*redB)[BM] = reinterpret_cast<float (*)[BM]>(&lds[0][0] + 1024);

  int bx = blockIdx.x;
  int t = threadIdx.x;
  int lane = t & 63;
  int wave = t >> 6;
  int l31 = lane & 31;
  int h = lane >> 5; // k-half within a k-step / row-half for C/D
  int rw = wave >> 1;
  int cw = wave & 1;
  const float scale = 1.4426950408889634f / 0.04f; // log2(e)/T

  bool smode = bx < S_BLOCKS;
  const unsigned char* X;
  const unsigned char* Y;
  int r0, c0, ga = 0, gb = 0, gg = 0;
  bool diagb = false;
  if (smode) {
    r0 = (bx >> 6) * BM;
    c0 = (bx & 63) * BM;
    X = q1; Y = q2;
  } else {
    int gx = bx - S_BLOCKS;
    gg = (gx >= TRI) ? 1 : 0;
    int tri = gx - gg * TRI;
    int a = (int)((sqrtf(8.0f * (float)tri + 1.0f) - 1.0f) * 0.5f);
    while ((a + 1) * (a + 2) / 2 <= tri) a++;
    while (a * (a + 1) / 2 > tri) a--;
    int b = tri - a * (a + 1) / 2; // b <= a
    ga = a; gb = b;
    X = gg ? q2 : q1; Y = X;
    r0 = a * BM;
    c0 = b * BM;
    diagb = (a == b);
  }

  // fragment LDS byte offsets. Register slot b of lane holds global k-bytes
  // [(ks*64)+(2h+b)*16, +16) -- identical numerics to the verified mapping.
  int offA[2][2], offB[2][2];
#pragma unroll
  for (int ks = 0; ks < 2; ks++) {
#pragma unroll
    for (int i = 0; i < 2; i++) {
      int rowa = rw * 64 + i * 32 + l31;
      offA[ks][i] = rowa * 128 + (((ks << 2) | (h << 1)) ^ (rowa & 7)) * 16;
      int rowb = cw * 64 + i * 32 + l31;
      offB[ks][i] = 16384 + rowb * 128 + (((ks << 2) | (h << 1)) ^ (rowb & 7)) * 16;
    }
  }

  // staging base pointers: thread t -> row = t>>3 (+32 per it), dest piece = t&7,
  // src piece = (t&7) ^ (row&7) = (t&7) ^ ((t>>3)&7)  (it-invariant: 32 % 8 == 0)
  int srow = t >> 3;
  int ssrc = (t & 7) ^ ((t >> 3) & 7);
  const unsigned char* pA = X + (size_t)(r0 + srow) * D + ssrc * 16;
  const unsigned char* pB = Y + (size_t)(c0 + srow) * D + ssrc * 16;

  f32x16 acc[2][2];
#pragma unroll
  for (int i = 0; i < 2; i++)
#pragma unroll
    for (int j = 0; j < 2; j++)
#pragma unroll
      for (int r = 0; r < 16; r++) acc[i][j][r] = 0.0f;

  stage_super(pA, pB, lds[0], t, 0);

  SG_ROUND(0) SG_ROUND(1) SG_ROUND(2) SG_ROUND(3)

  __syncthreads(); // ring dead; reuse as reduction scratch

  if (smode) {
    // ---- row + col sums of exp2(scale*g); fixed reference (fits fp32) ----
    float csum[2] = {0.0f, 0.0f};
#pragma unroll
    for (int i = 0; i < 2; i++) {
      float rsum[16];
#pragma unroll
      for (int reg = 0; reg < 16; reg++) rsum[reg] = 0.0f;
#pragma unroll
      for (int j = 0; j < 2; j++)
#pragma unroll
        for (int reg = 0; reg < 16; reg++) {
          float e = __builtin_amdgcn_exp2f(acc[i][j][reg] * scale);
          rsum[reg] += e;
          csum[j] += e;
        }
      // row-sum: reduce across the 32 lanes of this k/row-half (bit5 preserved)
#pragma unroll
      for (int reg = 0; reg < 16; reg++) {
#pragma unroll
        for (int off = 1; off < 32; off <<= 1) rsum[reg] += __shfl_xor(rsum[reg], off);
      }
      if (l31 == 0) {
#pragma unroll
        for (int reg = 0; reg < 16; reg++) {
          int rloc = (reg & 3) + 8 * (reg >> 2) + 4 * h;
          redB[cw][rw * 64 + i * 32 + rloc] = rsum[reg];
        }
      }
    }
    // col-sum: add the other row-half, then one lane-half writes
#pragma unroll
    for (int j = 0; j < 2; j++) {
      csum[j] += __shfl_xor(csum[j], 32);
      if (h == 0) redA[rw][cw * 64 + j * 32 + l31] = csum[j];
    }
    __syncthreads();
    if (t < BM) {
      colS[(size_t)(r0 >> 7) * N + c0 + t] = redA[0][t] + redA[1][t];
      rowS[(size_t)(c0 >> 7) * N + r0 + t] = redB[0][t] + redB[1][t];
    }
  } else {
    // ---- Gram: row max (strip a), diag-masked; col max = row max of strip b ----
#pragma unroll
    for (int i = 0; i < 2; i++) {
      float rmax[16];
#pragma unroll
      for (int reg = 0; reg < 16; reg++) {
        int rloc = (reg & 3) + 8 * (reg >> 2) + 4 * h;
        int rr = rw * 64 + i * 32 + rloc;
        float v = -3.0e38f;
#pragma unroll
        for (int j = 0; j < 2; j++) {
          float x = acc[i][j][reg];
          int cc = cw * 64 + j * 32 + l31;
          if (diagb && cc == rr) x = -3.0e38f;
          v = fmaxf(v, x);
        }
        rmax[reg] = v;
      }
#pragma unroll
      for (int reg = 0; reg < 16; reg++) {
#pragma unroll
        for (int off = 1; off < 32; off <<= 1) rmax[reg] = fmaxf(rmax[reg], __shfl_xor(rmax[reg], off));
      }
      if (l31 == 0) {
#pragma unroll
        for (int reg = 0; reg < 16; reg++) {
          int rloc = (reg & 3) + 8 * (reg >> 2) + 4 * h;
          redA[cw][rw * 64 + i * 32 + rloc] = rmax[reg];
        }
      }
    }
    if (!diagb) {
#pragma unroll
      for (int j = 0; j < 2; j++) {
        float m = -3.0e38f;
#pragma unroll
        for (int i = 0; i < 2; i++)
#pragma unroll
          for (int reg = 0; reg < 16; reg++) m = fmaxf(m, acc[i][j][reg]);
        m = fmaxf(m, __shfl_xor(m, 32));
        if (h == 0) redB[rw][cw * 64 + j * 32 + l31] = m;
      }
    }
    __syncthreads();
    if (t < BM) {
      partG[((size_t)(gg * NSTRIP + gb)) * N + r0 + t] = fmaxf(redA[0][t], redA[1][t]);
      if (!diagb)
        partG[((size_t)(gg * NSTRIP + ga)) * N + c0 + t] = fmaxf(redB[0][t], redB[1][t]);
    }
  }
}

// ---------------- per-row combine of partials -> atomic scalar ----------------
__global__ __launch_bounds__(256) void combine_kernel(
    const float* __restrict__ diag,
    const float* __restrict__ rowS, const float* __restrict__ colS,
    const float* __restrict__ partG, float* __restrict__ out) {
  int t = threadIdx.x;
  int l = t & 63;
  int w = t >> 6;
  int i = blockIdx.x * 64 + l;

  float sR = 0.0f, sC = 0.0f, g1 = -3.0e38f, g2 = -3.0e38f;
#pragma unroll
  for (int s = 0; s < 16; s++) {
    int strip = w * 16 + s;
    sR += rowS[(size_t)strip * N + i];
    sC += colS[(size_t)strip * N + i];
    g1 = fmaxf(g1, partG[(size_t)strip * N + i]);
    g2 = fmaxf(g2, partG[(size_t)(NSTRIP + strip) * N + i]);
  }
  __shared__ float red[4][4][64];
  red[0][w][l] = sR; red[1][w][l] = sC; red[2][w][l] = g1; red[3][w][l] = g2;
  __syncthreads();
  if (w == 0) {
    sR = red[0][0][l] + red[0][1][l] + red[0][2][l] + red[0][3][l];
    sC = red[1][0][l] + red[1][1][l] + red[1][2][l] + red[1][3][l];
    g1 = fmaxf(fmaxf(red[2][0][l], red[2][1][l]), fmaxf(red[2][2][l], red[2][3][l]));
    g2 = fmaxf(fmaxf(red[3][0][l], red[3][1][l]), fmaxf(red[3][2][l], red[3][3][l]));
    float dv = diag[i] * 25.0f;
    float a12 = logf(sR) - dv;
    float a21 = logf(sC) - dv;
    float k1 = logf(sqrtf(fmaxf(2.0f - 2.0f * g1, 0.0f)) + 1e-9f);
    float k2 = logf(sqrtf(fmaxf(2.0f - 2.0f * g2, 0.0f)) + 1e-9f);
    float c = 0.5f * (a12 + a21) / (float)N - 0.1f * 0.5f * (k1 + k2) / (float)N;
#pragma unroll
    for (int off = 1; off < 64; off <<= 1) c += __shfl_xor(c, off);
    if (l == 0) atomicAdd(out, c); // device-scope, out zeroed by norm_kernel
  }
}

extern "C" void kernel_launch(void* const* d_in, const int* in_sizes, int n_in,
                              void* d_out, int out_size, void* d_ws, size_t ws_size,
                              hipStream_t stream) {
  const float* z1 = (const float*)d_in[0];
  const float* z2 = (const float*)d_in[1];
  char* w = (char*)d_ws;
  unsigned char* q1 = (unsigned char*)w; w += (size_t)N * D;
  unsigned char* q2 = (unsigned char*)w; w += (size_t)N * D;
  float* diag = (float*)w;   w += (size_t)N * sizeof(float);
  float* rowS = (float*)w;   w += (size_t)NSTRIP * N * sizeof(float);
  float* colS = (float*)w;   w += (size_t)NSTRIP * N * sizeof(float);
  float* partG = (float*)w;  w += (size_t)2 * NSTRIP * N * sizeof(float);
  float* out = (float*)d_out;

  norm_kernel<<<N / 4, 256, 0, stream>>>(z1, z2, q1, q2, diag, out);
  sg_kernel<<<SG_BLOCKS, 256, 0, stream>>>(q1, q2, rowS, colS, partG);
  combine_kernel<<<N / 64, 256, 0, stream>>>(diag, rowS, colS, partG, out);
}